// Round 5
// baseline (100.104 us; speedup 1.0000x reference)
//
#include <hip/hip_runtime.h>
#include <hip/hip_bf16.h>
#include <math.h>

// ABMIL gated-attention pooling, one streaming pass, single kernel.
// a = tanh(x.w1)*sigmoid(x.w2) bounded in (-1,1) -> no softmax max-trick
// needed; masked rows contribute exactly 0 (exp(-10000) underflows) and are
// never loaded. out = (z@wf^T)/s is linear in z -> each block reduces to
// {pd[4], s} and atomically accumulates into 20 global floats; the last
// block normalizes and writes out[16]. 2048 blocks (2 generations) so the
// dispatcher load-balances the binomial valid-count variance across CUs.
// NOTE: per-row p is wave-uniform (post-butterfly) -> s is uniform, never
// wave_reduce it (R3 lesson).

#define NB   4
#define NN   16384
#define DD   1024
#define LL   4
#define RPB  32                  // rows per block
#define RPW  8                   // rows per wave (4 waves)
#define GX   (NN / RPB)          // 512 blocks per bag
#define NBLK (GX * NB)           // 2048 total blocks

__device__ __forceinline__ float wave_reduce(float v) {
    #pragma unroll
    for (int off = 32; off > 0; off >>= 1) v += __shfl_xor(v, off, 64);
    return v;
}

__device__ __forceinline__ float fast_rcp(float x) {
    return __builtin_amdgcn_rcpf(x);
}

// pop lowest set bit index; -1 if empty. m is wave-uniform -> scalar ops.
__device__ __forceinline__ int popnext(unsigned& m) {
    if (m == 0u) return -1;
    const int i = (int)__builtin_ctz(m);
    m &= m - 1u;
    return i;
}

// ws layout (floats): [0:16) pd accum (bag*4+l), [16:20) s accum, [20] done
struct Accum { float pd[NB * LL]; float s[NB]; unsigned done; };

__global__ __launch_bounds__(256, 4) void abmil_main(
    const float* __restrict__ xs, const void* __restrict__ valid,
    const float* __restrict__ w1, const float* __restrict__ w2,
    const float* __restrict__ wf, Accum* __restrict__ acc,
    float* __restrict__ out) {
    const int blk  = blockIdx.x;
    const int bag  = blockIdx.y;
    const int tid  = threadIdx.x;
    const int wave = tid >> 6;
    const int lane = tid & 63;

    // ---- wave-local dtype detect: 1 load + 2 ballots, no LDS/sync ----
    // First row of every bag is guaranteed valid, so among the first 16
    // words: int32 -> all in {0,1}; f32 -> {0, 0x3F800000}; byte -> some
    // word has nonzero high bytes (p(miss) ~ 8^-16).
    const unsigned wd = ((const unsigned*)valid)[lane & 15];
    const unsigned long long bi = __ballot(wd != 0u && wd != 1u);
    const unsigned long long bf = __ballot(wd != 0u && wd != 0x3F800000u);
    const int mode = (bi == 0ull) ? 1 : ((bf == 0ull) ? 2 : 0);

    // ---- gate weights into registers (16 f32/lane each) ----
    const float4* w1v = (const float4*)w1;
    const float4* w2v = (const float4*)w2;
    float4 w1r[4], w2r[4];
    #pragma unroll
    for (int k = 0; k < 4; ++k) {
        w1r[k] = w1v[k * 64 + lane];
        w2r[k] = w2v[k * 64 + lane];
    }

    // ---- validity mask for this wave's 8 rows ----
    const int n0 = blk * RPB + wave * RPW;
    int flag = 0;
    if (lane < RPW) {
        const size_t idx = (size_t)bag * NN + n0 + lane;
        if (mode == 1)      flag = ((const int*)valid)[idx] != 0;
        else if (mode == 2) flag = ((const float*)valid)[idx] != 0.0f;
        else                flag = ((const unsigned char*)valid)[idx] != 0;
    }
    unsigned m = (unsigned)(__ballot(flag) & 0xFFull);

    // ---- accumulators ----
    float s = 0.0f;   // wave-uniform
    float4 z[4];
    #pragma unroll
    for (int k = 0; k < 4; ++k) z[k] = make_float4(0.f, 0.f, 0.f, 0.f);

    const float4* xbase = (const float4*)(xs + (size_t)bag * NN * DD);

    auto loadrow = [&](float4 (&xr)[4], int idx) {
        if (idx >= 0) {
            const float4* xp = xbase + (size_t)(n0 + idx) * (DD / 4);
            #pragma unroll
            for (int k = 0; k < 4; ++k) xr[k] = xp[k * 64 + lane];
        }
    };
    auto comprow = [&](const float4 (&xr)[4]) {
        float d1 = 0.f, d2 = 0.f;
        #pragma unroll
        for (int k = 0; k < 4; ++k) {
            d1 += xr[k].x * w1r[k].x + xr[k].y * w1r[k].y +
                  xr[k].z * w1r[k].z + xr[k].w * w1r[k].w;
            d2 += xr[k].x * w2r[k].x + xr[k].y * w2r[k].y +
                  xr[k].z * w2r[k].z + xr[k].w * w2r[k].w;
        }
        #pragma unroll
        for (int off = 32; off > 0; off >>= 1) {
            d1 += __shfl_xor(d1, off, 64);
            d2 += __shfl_xor(d2, off, 64);
        }
        // tanh via exp identity (overflow-safe), sigmoid via rcp
        const float e  = __expf(-2.0f * fabsf(d1));
        const float t  = copysignf((1.0f - e) * fast_rcp(1.0f + e), d1);
        const float sg = fast_rcp(1.0f + __expf(-d2));
        const float p  = __expf(t * sg);
        s += p;
        #pragma unroll
        for (int k = 0; k < 4; ++k) {
            z[k].x += p * xr[k].x; z[k].y += p * xr[k].y;
            z[k].z += p * xr[k].z; z[k].w += p * xr[k].w;
        }
    };

    // ---- depth-2 pipelined loop over valid rows only ----
    float4 xA[4], xB[4];
    int iA = popnext(m), iB = popnext(m);
    loadrow(xA, iA); loadrow(xB, iB);
    for (;;) {
        if (iA < 0) break;
        comprow(xA); iA = popnext(m); loadrow(xA, iA);
        if (iB < 0) break;
        comprow(xB); iB = popnext(m); loadrow(xB, iB);
    }

    // ---- project z onto wf rows (global reads, L2-hot) ----
    const float4* wfv = (const float4*)wf;
    float pl[LL] = {0.f, 0.f, 0.f, 0.f};
    #pragma unroll
    for (int l = 0; l < LL; ++l) {
        #pragma unroll
        for (int k = 0; k < 4; ++k) {
            const float4 wv = wfv[l * 256 + k * 64 + lane];
            pl[l] += z[k].x * wv.x + z[k].y * wv.y +
                     z[k].z * wv.z + z[k].w * wv.w;
        }
    }
    #pragma unroll
    for (int l = 0; l < LL; ++l) pl[l] = wave_reduce(pl[l]);

    // ---- block combine via LDS, then 5 device atomics ----
    __shared__ float comb[4][LL];
    __shared__ float scomb[4];
    __shared__ int   lastf;
    if (lane == 0) {
        #pragma unroll
        for (int l = 0; l < LL; ++l) comb[wave][l] = pl[l];
        scomb[wave] = s;   // uniform: take directly, no reduce
    }
    __syncthreads();

    if (tid < LL)
        atomicAdd(&acc->pd[bag * LL + tid],
                  comb[0][tid] + comb[1][tid] + comb[2][tid] + comb[3][tid]);
    if (tid == LL)
        atomicAdd(&acc->s[bag], scomb[0] + scomb[1] + scomb[2] + scomb[3]);
    if (tid <= LL) __threadfence();   // make our adds device-visible
    __syncthreads();

    if (tid == 0) {
        const unsigned r = atomicAdd(&acc->done, 1u);
        lastf = (r == (unsigned)(NBLK - 1));
    }
    __syncthreads();

    if (lastf && tid < NB * LL) {
        __threadfence();
        const float pd = atomicAdd(&acc->pd[tid], 0.0f);   // coherent read
        const float sv = atomicAdd(&acc->s[tid >> 2], 0.0f);
        out[tid] = pd / sv;
    }
}

// ---------------------------------------------------------------------------
extern "C" void kernel_launch(void* const* d_in, const int* in_sizes, int n_in,
                              void* d_out, int out_size, void* d_ws, size_t ws_size,
                              hipStream_t stream) {
    const float* xs    = (const float*)d_in[0];
    const void*  valid = d_in[1];
    const float* w1    = (const float*)d_in[2];
    const float* w2    = (const float*)d_in[3];
    const float* wf    = (const float*)d_in[4];
    float* out = (float*)d_out;
    Accum* acc = (Accum*)d_ws;

    // zero accumulators + done counter each call (graph-capturable)
    hipMemsetAsync(d_ws, 0, sizeof(Accum), stream);

    dim3 g0(GX, NB);
    abmil_main<<<g0, 256, 0, stream>>>(xs, valid, w1, w2, wf, acc, out);
}